// Round 2
// baseline (66.113 us; speedup 1.0000x reference)
//
#include <hip/hip_runtime.h>
#include <math.h>

#define NNODE 512
#define NBATCH 4
#define NFEAT 12
#define QKD 128
#define NVD 128
#define EVD 32
#define CATD 160          // NVD + EVD
#define TRD 256
#define NCLS 5
#define TI 4              // query rows per block in attn kernel
#define NROWS 2048        // NBATCH * NNODE
#define EPSV 1e-5f
#define NSTATBUF 8        // split atomic contention 8 ways

// ---------------------------------------------------------------------------
// Kernel 1: Q, K, NV projections (2048 rows x 12 -> 128 each). Blocks 0..31
// zero the 8x512-float BN-stats region.
// ---------------------------------------------------------------------------
__global__ __launch_bounds__(128) void qkv_kernel(
    const float* __restrict__ nodes,
    const float* __restrict__ Wq, const float* __restrict__ bq,
    const float* __restrict__ Wk, const float* __restrict__ bk,
    const float* __restrict__ Wnv, const float* __restrict__ bnv,
    float* __restrict__ Q, float* __restrict__ K, float* __restrict__ NV,
    float* __restrict__ stats) {
  const int row = blockIdx.x;      // 0..2047
  const int d   = threadIdx.x;     // 0..127
  if (row < NSTATBUF * 4)          // 32 blocks x 128 = 4096 floats
    stats[row * 128 + d] = 0.f;
  __shared__ float sn[NFEAT];
  if (d < NFEAT) sn[d] = nodes[row * NFEAT + d];
  __syncthreads();
  float aq = bq[d], ak = bk[d], av = bnv[d];
#pragma unroll
  for (int k = 0; k < NFEAT; ++k) {
    const float n = sn[k];
    aq = fmaf(n, Wq[d * NFEAT + k], aq);
    ak = fmaf(n, Wk[d * NFEAT + k], ak);
    av = fmaf(n, Wnv[d * NFEAT + k], av);
  }
  Q[row * QKD + d]  = aq;
  K[row * QKD + d]  = ak;
  NV[row * NVD + d] = av;
}

// ---------------------------------------------------------------------------
// Kernel 2: per block = 4 query rows of one batch (grid 512 -> 2 blocks/CU).
//   phase1: scores QK^T * coeff / (dist+1), mask -> -inf      (thread = j)
//   phase2: softmax per row (waves 0..3), + sum_w, sum_w*e
//   phase3: node_part = w @ NV (j-split over 4 groups, LDS combine)
//   out:    cat[row][0:128]=tanh(node_part), cat[row][128:160]=tanh(edge part)
// ---------------------------------------------------------------------------
__global__ __launch_bounds__(512) void attn_kernel(
    const float* __restrict__ Q, const float* __restrict__ K,
    const float* __restrict__ NV,
    const float* __restrict__ edges, const float* __restrict__ dist,
    const int* __restrict__ mask,
    const float* __restrict__ Wev, const float* __restrict__ bev,
    float* __restrict__ cat) {
  __shared__ __align__(16) float sQ[TI][QKD];     // 2 KB
  __shared__ __align__(16) float sS[TI][NNODE];   // 8 KB (scores->w->partials)
  __shared__ float sSW[TI], sSE[TI];

  const int tid = threadIdx.x;
  const int bid = blockIdx.x;          // 0..511
  const int b   = bid >> 7;            // 128 blocks per batch
  const int i0  = (bid & 127) * TI;
  const int rowbase = b * NNODE + i0;

  // stage Q rows: 4*128 = 512 elements, one per thread
  sQ[tid >> 7][tid & 127] = Q[(size_t)(rowbase + (tid >> 7)) * QKD + (tid & 127)];
  __syncthreads();

  // ---- phase 1: scores -------------------------------------------------
  {
    const int j = tid;  // 0..511
    const float4* K4 = (const float4*)(K + (size_t)(b * NNODE + j) * QKD);
    float acc[TI] = {0.f, 0.f, 0.f, 0.f};
#pragma unroll 8
    for (int kk = 0; kk < QKD / 4; ++kk) {
      const float4 kv = K4[kk];
#pragma unroll
      for (int ii = 0; ii < TI; ++ii) {
        const float4 qv = ((const float4*)sQ[ii])[kk];
        acc[ii] += qv.x * kv.x + qv.y * kv.y + qv.z * kv.z + qv.w * kv.w;
      }
    }
    const float coeff = 0.0883883476483184f;  // 1/sqrt(128)
#pragma unroll
    for (int ii = 0; ii < TI; ++ii) {
      const size_t off = (size_t)(rowbase + ii) * NNODE + j;
      float s = acc[ii] * coeff / (dist[off] + 1.0f);
      if (mask[off] != 0) s = -__builtin_inff();
      sS[ii][j] = s;
    }
  }
  __syncthreads();

  // ---- phase 2: softmax (waves 0..3, one per row) + row sums -----------
  if (tid < TI * 64) {
    const int i    = tid >> 6;
    const int lane = tid & 63;
    float v[NNODE / 64];
    float m = -__builtin_inff();
#pragma unroll
    for (int t = 0; t < NNODE / 64; ++t) {
      v[t] = sS[i][lane + 64 * t];
      m = fmaxf(m, v[t]);
    }
#pragma unroll
    for (int s = 1; s < 64; s <<= 1) m = fmaxf(m, __shfl_xor(m, s, 64));
    float sum = 0.f;
    if (m > -__builtin_inff()) {          // wave-uniform branch
#pragma unroll
      for (int t = 0; t < NNODE / 64; ++t) { v[t] = __expf(v[t] - m); sum += v[t]; }
    } else {                              // fully-masked row -> zero weights
#pragma unroll
      for (int t = 0; t < NNODE / 64; ++t) v[t] = 0.f;
    }
#pragma unroll
    for (int s = 1; s < 64; s <<= 1) sum += __shfl_xor(sum, s, 64);
    const float inv = (sum > 0.f) ? 1.f / sum : 0.f;
    const float* erow = edges + (size_t)(rowbase + i) * NNODE;
    float sw = 0.f, se = 0.f;
#pragma unroll
    for (int t = 0; t < NNODE / 64; ++t) {
      const float w = v[t] * inv;
      sS[i][lane + 64 * t] = w;
      sw += w;
      se = fmaf(w, erow[lane + 64 * t], se);
    }
#pragma unroll
    for (int s = 1; s < 64; s <<= 1) {
      sw += __shfl_xor(sw, s, 64);
      se += __shfl_xor(se, s, 64);
    }
    if (lane == 0) { sSW[i] = sw; sSE[i] = se; }
  }
  __syncthreads();

  // ---- phase 3: node_part = w @ NV, j-split over 4 thread groups -------
  {
    const int d = tid & 127;
    const int g = tid >> 7;        // 0..3, each group owns 128 j's
    float acc[TI] = {0.f, 0.f, 0.f, 0.f};
    const float* __restrict__ NVb = NV + (size_t)b * NNODE * NVD + d;
    const int j0 = g * 128;
#pragma unroll 8
    for (int jj = 0; jj < 128; ++jj) {
      const int j = j0 + jj;
      const float nv = NVb[(size_t)j * NVD];
#pragma unroll
      for (int ii = 0; ii < TI; ++ii) acc[ii] = fmaf(sS[ii][j], nv, acc[ii]);
    }
    __syncthreads();               // everyone done reading w from sS
    float* part = &sS[0][0];       // reuse as [4][TI][128] partials
#pragma unroll
    for (int ii = 0; ii < TI; ++ii) part[(g * TI + ii) * 128 + d] = acc[ii];
  }
  __syncthreads();

  // ---- combine partials, tanh, write cat -------------------------------
  {
    const float* part = &sS[0][0];
    const int ii = tid >> 7, d = tid & 127;
    const float v = part[(0 * TI + ii) * 128 + d] + part[(1 * TI + ii) * 128 + d]
                  + part[(2 * TI + ii) * 128 + d] + part[(3 * TI + ii) * 128 + d];
    cat[(size_t)(rowbase + ii) * CATD + d] = tanhf(v);
    if (tid < TI * EVD) {          // edge part: Wev*se + bev*sw (EF==1 collapse)
      const int ie = tid >> 5, de = tid & 31;
      cat[(size_t)(rowbase + ie) * CATD + NVD + de] =
          tanhf(fmaf(Wev[de], sSE[ie], bev[de] * sSW[ie]));
    }
  }
}

// ---------------------------------------------------------------------------
// Kernel 3: vals = cat @ Wt^T + bt  (M=2048, K=160, N=256) + BN stat atomics.
// grid 256 x 512 thr; 8 rows/block; o = tid&255, h = tid>>8 owns 4 rows.
// ---------------------------------------------------------------------------
__global__ __launch_bounds__(512) void trans_kernel(
    const float* __restrict__ cat,
    const float* __restrict__ Wt, const float* __restrict__ bt,
    float* __restrict__ vals, float* __restrict__ stats) {
  __shared__ __align__(16) float sC[8][CATD];     // 5 KB
  __shared__ float sWt[TRD * 33];                 // 33.8 KB (padded tile)
  const int tid = threadIdx.x;
  const int bid = blockIdx.x;          // 0..255
  const int row0 = bid * 8;

  for (int idx = tid; idx < 8 * CATD; idx += 512) {
    const int r = idx / CATD, k = idx - r * CATD;
    sC[r][k] = cat[(size_t)(row0 + r) * CATD + k];
  }

  const int o = tid & 255;
  const int h = tid >> 8;              // 0..1 -> rows h*4 .. h*4+3
  float acc[4] = {0.f, 0.f, 0.f, 0.f};
  for (int kc = 0; kc < CATD; kc += 32) {
    __syncthreads();                   // protect sWt from previous readers
    for (int idx = tid; idx < TRD * 32; idx += 512) {
      const int oo = idx >> 5, kk = idx & 31;
      sWt[oo * 33 + kk] = Wt[oo * CATD + kc + kk];
    }
    __syncthreads();
#pragma unroll
    for (int kk = 0; kk < 32; ++kk) {
      const float w = sWt[o * 33 + kk];
#pragma unroll
      for (int q = 0; q < 4; ++q)
        acc[q] = fmaf(sC[h * 4 + q][kc + kk], w, acc[q]);
    }
  }
  const float bto = bt[o];
  float s1 = 0.f, s2 = 0.f;
#pragma unroll
  for (int q = 0; q < 4; ++q) {
    const float v2 = acc[q] + bto;
    vals[(size_t)(row0 + h * 4 + q) * TRD + o] = v2;
    s1 += v2;
    s2 = fmaf(v2, v2, s2);
  }
  float* sb = stats + (size_t)(bid & (NSTATBUF - 1)) * 2 * TRD;
  atomicAdd(&sb[o], s1);
  atomicAdd(&sb[TRD + o], s2);
}

// ---------------------------------------------------------------------------
// Kernel 4: fold BN (biased batch stats) + gamma/beta into classifier:
//   Weff[c][o] = Wc[c][o]*gamma[o]*inv[o]
//   beff[c]    = bc[c] + sum_o (beta[o]-mu[o]*gamma[o]*inv[o])*Wc[c][o]
// ---------------------------------------------------------------------------
__global__ __launch_bounds__(256) void bnprep_kernel(
    const float* __restrict__ stats,
    const float* __restrict__ gamma, const float* __restrict__ beta,
    const float* __restrict__ Wc, const float* __restrict__ bc,
    float* __restrict__ Weff, float* __restrict__ beff) {
  const int o = threadIdx.x;           // 0..255
  float s1 = 0.f, s2 = 0.f;
#pragma unroll
  for (int k = 0; k < NSTATBUF; ++k) {
    s1 += stats[k * 2 * TRD + o];
    s2 += stats[k * 2 * TRD + TRD + o];
  }
  const float invN = 1.0f / (float)NROWS;
  const float mu  = s1 * invN;
  const float var = s2 * invN - mu * mu;
  const float inv = 1.0f / sqrtf(var + EPSV);
  const float g = gamma[o] * inv;
  const float bterm = beta[o] - mu * g;
  float v[NCLS];
#pragma unroll
  for (int c = 0; c < NCLS; ++c) {
    const float wc = Wc[c * TRD + o];
    Weff[c * TRD + o] = wc * g;
    v[c] = wc * bterm;
  }
#pragma unroll
  for (int s = 1; s < 64; s <<= 1) {
#pragma unroll
    for (int c = 0; c < NCLS; ++c) v[c] += __shfl_xor(v[c], s, 64);
  }
  __shared__ float red[4][NCLS];
  if ((o & 63) == 0) {
#pragma unroll
    for (int c = 0; c < NCLS; ++c) red[o >> 6][c] = v[c];
  }
  __syncthreads();
  if (o < NCLS)
    beff[o] = bc[o] + red[0][o] + red[1][o] + red[2][o] + red[3][o];
}

// ---------------------------------------------------------------------------
// Kernel 5: out[row][c] = vals[row] . Weff[c] + beff[c]   (wave per row)
// ---------------------------------------------------------------------------
__global__ __launch_bounds__(256) void out_kernel(
    const float* __restrict__ vals,
    const float* __restrict__ Weff, const float* __restrict__ beff,
    float* __restrict__ out) {
  __shared__ float sW[NCLS][TRD];
  __shared__ float sb[NCLS];
  const int tid = threadIdx.x;
  for (int idx = tid; idx < NCLS * TRD; idx += 256)
    sW[idx >> 8][idx & 255] = Weff[idx];
  if (tid < NCLS) sb[tid] = beff[tid];
  __syncthreads();
  const int lane = tid & 63;
  const int row = blockIdx.x * 4 + (tid >> 6);   // 512 blocks x 4 rows
  float v[TRD / 64];
#pragma unroll
  for (int t = 0; t < TRD / 64; ++t)
    v[t] = vals[(size_t)row * TRD + lane + 64 * t];
#pragma unroll
  for (int c = 0; c < NCLS; ++c) {
    float p = 0.f;
#pragma unroll
    for (int t = 0; t < TRD / 64; ++t)
      p = fmaf(v[t], sW[c][lane + 64 * t], p);
#pragma unroll
    for (int s = 1; s < 64; s <<= 1) p += __shfl_xor(p, s, 64);
    if (lane == 0) out[(size_t)row * NCLS + c] = p + sb[c];
  }
}

// ---------------------------------------------------------------------------
extern "C" void kernel_launch(void* const* d_in, const int* in_sizes, int n_in,
                              void* d_out, int out_size, void* d_ws, size_t ws_size,
                              hipStream_t stream) {
  (void)in_sizes; (void)n_in; (void)out_size; (void)ws_size;
  const float* nodes = (const float*)d_in[0];
  const float* edges = (const float*)d_in[1];
  const float* dist  = (const float*)d_in[2];
  const int*   mask  = (const int*)d_in[3];
  const float* Wq  = (const float*)d_in[4];
  const float* bq  = (const float*)d_in[5];
  const float* Wk  = (const float*)d_in[6];
  const float* bk  = (const float*)d_in[7];
  const float* Wnv = (const float*)d_in[8];
  const float* bnv = (const float*)d_in[9];
  const float* Wev = (const float*)d_in[10];
  const float* bev = (const float*)d_in[11];
  const float* Wt  = (const float*)d_in[12];
  const float* bt  = (const float*)d_in[13];
  const float* gamma = (const float*)d_in[14];
  const float* beta  = (const float*)d_in[15];
  const float* Wc  = (const float*)d_in[16];
  const float* bc  = (const float*)d_in[17];

  float* ws    = (float*)d_ws;
  float* Q     = ws;                               // 2048*128
  float* K     = Q  + (size_t)NROWS * QKD;         // 2048*128
  float* NV    = K  + (size_t)NROWS * QKD;         // 2048*128
  float* cat   = NV + (size_t)NROWS * NVD;         // 2048*160
  float* vals  = cat + (size_t)NROWS * CATD;       // 2048*256
  float* stats = vals + (size_t)NROWS * TRD;       // 8*512 (sum|sqsum buffers)
  float* Weff  = stats + NSTATBUF * 2 * TRD;       // 5*256
  float* beff  = Weff + NCLS * TRD;                // 5
  float* outp  = (float*)d_out;

  qkv_kernel<<<NROWS, 128, 0, stream>>>(nodes, Wq, bq, Wk, bk, Wnv, bnv, Q, K, NV, stats);
  attn_kernel<<<NROWS / TI, 512, 0, stream>>>(Q, K, NV, edges, dist, mask,
                                              Wev, bev, cat);
  trans_kernel<<<NROWS / 8, 512, 0, stream>>>(cat, Wt, bt, vals, stats);
  bnprep_kernel<<<1, TRD, 0, stream>>>(stats, gamma, beta, Wc, bc, Weff, beff);
  out_kernel<<<NROWS / 4, 256, 0, stream>>>(vals, Weff, beff, outp);
}

// Round 3
// 62.489 us; speedup vs baseline: 1.0580x; 1.0580x over previous
//
#include <hip/hip_runtime.h>
#include <math.h>

#define NNODE 512
#define NBATCH 4
#define NFEAT 12
#define QKD 128
#define NVD 128
#define EVD 32
#define CATD 160          // NVD + EVD
#define TRD 256
#define NCLS 5
#define TI 4              // query rows per attn block
#define NROWS 2048        // NBATCH * NNODE
#define EPSV 1e-5f
#define NSTATBUF 8        // split BN-stat atomic contention 8 ways

// ---------------------------------------------------------------------------
// Kernel 1: Q, K, NV projections. 256 thr, 2 rows/block, grid 1024.
// Blocks 0..15 zero the 8x512-float BN-stats region.
// ---------------------------------------------------------------------------
__global__ __launch_bounds__(256) void qkv_kernel(
    const float* __restrict__ nodes,
    const float* __restrict__ Wq, const float* __restrict__ bq,
    const float* __restrict__ Wk, const float* __restrict__ bk,
    const float* __restrict__ Wnv, const float* __restrict__ bnv,
    float* __restrict__ Q, float* __restrict__ K, float* __restrict__ NV,
    float* __restrict__ stats) {
  const int tid = threadIdx.x;
  const int h = tid >> 7, d = tid & 127;
  const int row = blockIdx.x * 2 + h;
  if (blockIdx.x < 2 * NSTATBUF)       // 16 blocks x 256 = 4096 floats
    stats[blockIdx.x * 256 + tid] = 0.f;
  __shared__ float sn[2][NFEAT];
  if (tid < 2 * NFEAT) sn[tid / NFEAT][tid % NFEAT] = nodes[blockIdx.x * 2 * NFEAT + tid];
  __syncthreads();
  float aq = bq[d], ak = bk[d], av = bnv[d];
#pragma unroll
  for (int k = 0; k < NFEAT; ++k) {
    const float n = sn[h][k];
    aq = fmaf(n, Wq[d * NFEAT + k], aq);
    ak = fmaf(n, Wk[d * NFEAT + k], ak);
    av = fmaf(n, Wnv[d * NFEAT + k], av);
  }
  Q[row * QKD + d]  = aq;
  K[row * QKD + d]  = ak;
  NV[row * NVD + d] = av;
}

// ---------------------------------------------------------------------------
// Kernel 2: attn. 256 thr (4 waves), TI=4 rows, thread owns j and j+256.
//   phase1: prefetch dist/mask -> scores QK^T * coeff/(dist+1), mask->-inf
//   phase2: softmax (wave i = row i) + sum_w, sum_w*e
//   phase3: node_part = w @ NV (2 j-groups), LDS combine
//   out:    cat[row] = tanh(node_part | edge_part)
// ---------------------------------------------------------------------------
__global__ __launch_bounds__(256) void attn_kernel(
    const float* __restrict__ Q, const float* __restrict__ K,
    const float* __restrict__ NV,
    const float* __restrict__ edges, const float* __restrict__ dist,
    const int* __restrict__ mask,
    const float* __restrict__ Wev, const float* __restrict__ bev,
    float* __restrict__ cat) {
  __shared__ __align__(16) float sQ[TI][QKD];     // 2 KB
  __shared__ __align__(16) float sS[TI][NNODE];   // 8 KB (scores->w->partials)
  __shared__ float sSW[TI], sSE[TI];

  const int tid = threadIdx.x;
  const int bid = blockIdx.x;          // 0..511
  const int b   = bid >> 7;            // 128 blocks per batch
  const int i0  = (bid & 127) * TI;
  const int rowbase = b * NNODE + i0;

  // stage Q rows (contiguous 512 floats), 2 per thread
  ((float*)sQ)[tid]       = Q[(size_t)rowbase * QKD + tid];
  ((float*)sQ)[tid + 256] = Q[(size_t)rowbase * QKD + tid + 256];
  __syncthreads();

  // ---- phase 1: scores for columns j=tid and j=tid+256 -----------------
  {
    // prefetch dist/mask first (independent of the dot products)
    float da[TI], db[TI];
    int   ma[TI], mb[TI];
#pragma unroll
    for (int ii = 0; ii < TI; ++ii) {
      const size_t off = (size_t)(rowbase + ii) * NNODE;
      da[ii] = dist[off + tid];       db[ii] = dist[off + tid + 256];
      ma[ii] = mask[off + tid];       mb[ii] = mask[off + tid + 256];
    }
    const float4* Ka = (const float4*)(K + (size_t)(b * NNODE + tid) * QKD);
    const float4* Kb = Ka + 256 * (QKD / 4);
    float acc0[TI] = {0.f, 0.f, 0.f, 0.f};
    float acc1[TI] = {0.f, 0.f, 0.f, 0.f};
#pragma unroll 4
    for (int kk = 0; kk < QKD / 4; ++kk) {
      const float4 ka = Ka[kk];
      const float4 kb = Kb[kk];
#pragma unroll
      for (int ii = 0; ii < TI; ++ii) {
        const float4 qv = ((const float4*)sQ[ii])[kk];
        acc0[ii] += qv.x * ka.x + qv.y * ka.y + qv.z * ka.z + qv.w * ka.w;
        acc1[ii] += qv.x * kb.x + qv.y * kb.y + qv.z * kb.z + qv.w * kb.w;
      }
    }
    const float coeff = 0.0883883476483184f;  // 1/sqrt(128)
#pragma unroll
    for (int ii = 0; ii < TI; ++ii) {
      float s0 = acc0[ii] * coeff / (da[ii] + 1.0f);
      if (ma[ii]) s0 = -__builtin_inff();
      sS[ii][tid] = s0;
      float s1 = acc1[ii] * coeff / (db[ii] + 1.0f);
      if (mb[ii]) s1 = -__builtin_inff();
      sS[ii][tid + 256] = s1;
    }
  }
  __syncthreads();

  // ---- phase 2: softmax (4 waves, wave i = row i) + row sums -----------
  {
    const int i    = tid >> 6;
    const int lane = tid & 63;
    float v[NNODE / 64];
    float m = -__builtin_inff();
#pragma unroll
    for (int t = 0; t < NNODE / 64; ++t) {
      v[t] = sS[i][lane + 64 * t];
      m = fmaxf(m, v[t]);
    }
#pragma unroll
    for (int s = 1; s < 64; s <<= 1) m = fmaxf(m, __shfl_xor(m, s, 64));
    float sum = 0.f;
    if (m > -__builtin_inff()) {          // wave-uniform branch
#pragma unroll
      for (int t = 0; t < NNODE / 64; ++t) { v[t] = __expf(v[t] - m); sum += v[t]; }
    } else {                              // fully-masked row -> zero weights
#pragma unroll
      for (int t = 0; t < NNODE / 64; ++t) v[t] = 0.f;
    }
#pragma unroll
    for (int s = 1; s < 64; s <<= 1) sum += __shfl_xor(sum, s, 64);
    const float inv = (sum > 0.f) ? 1.f / sum : 0.f;
    const float* erow = edges + (size_t)(rowbase + i) * NNODE;
    float sw = 0.f, se = 0.f;
#pragma unroll
    for (int t = 0; t < NNODE / 64; ++t) {
      const float w = v[t] * inv;
      sS[i][lane + 64 * t] = w;
      sw += w;
      se = fmaf(w, erow[lane + 64 * t], se);
    }
#pragma unroll
    for (int s = 1; s < 64; s <<= 1) {
      sw += __shfl_xor(sw, s, 64);
      se += __shfl_xor(se, s, 64);
    }
    if (lane == 0) { sSW[i] = sw; sSE[i] = se; }
  }
  __syncthreads();

  // ---- phase 3: node_part = w @ NV, j-split over 2 thread groups -------
  {
    const int d = tid & 127;
    const int g = tid >> 7;        // 0..1, each group owns 256 j's
    float acc[TI] = {0.f, 0.f, 0.f, 0.f};
    const float* __restrict__ NVb = NV + (size_t)b * NNODE * NVD + d;
    const int j0 = g * 256;
#pragma unroll 8
    for (int jj = 0; jj < 256; ++jj) {
      const int j = j0 + jj;
      const float nv = NVb[(size_t)j * NVD];
#pragma unroll
      for (int ii = 0; ii < TI; ++ii) acc[ii] = fmaf(sS[ii][j], nv, acc[ii]);
    }
    __syncthreads();               // everyone done reading w from sS
    float* part = &sS[0][0];       // reuse as [2][TI][128] partials
#pragma unroll
    for (int ii = 0; ii < TI; ++ii) part[(g * TI + ii) * 128 + d] = acc[ii];
  }
  __syncthreads();

  // ---- combine partials, tanh, write cat -------------------------------
  {
    const float* part = &sS[0][0];
#pragma unroll
    for (int k = 0; k < 2; ++k) {
      const int idx = tid + k * 256;
      const int ii = idx >> 7, d = idx & 127;
      const float v = part[ii * 128 + d] + part[(TI + ii) * 128 + d];
      cat[(size_t)(rowbase + ii) * CATD + d] = tanhf(v);
    }
    if (tid < TI * EVD) {          // edge part: Wev*se + bev*sw (EF==1 collapse)
      const int ie = tid >> 5, de = tid & 31;
      cat[(size_t)(rowbase + ie) * CATD + NVD + de] =
          tanhf(fmaf(Wev[de], sSE[ie], bev[de] * sSW[ie]));
    }
  }
}

// ---------------------------------------------------------------------------
// Kernel 3: vals = cat @ Wt^T + bt  (M=2048,K=160,N=256) + BN stat atomics.
// 512 blocks x 256 thr; 4 rows/block; thread owns output column o = tid and
// streams its own Wt row as float4 (L1-line reuse), cat broadcast from LDS.
// ---------------------------------------------------------------------------
__global__ __launch_bounds__(256) void trans_kernel(
    const float* __restrict__ cat,
    const float* __restrict__ Wt, const float* __restrict__ bt,
    float* __restrict__ vals, float* __restrict__ stats) {
  __shared__ __align__(16) float sC[4][CATD];     // 2.5 KB
  const int tid = threadIdx.x;
  const int bid = blockIdx.x;          // 0..511
  const int row0 = bid * 4;

  for (int idx = tid; idx < 4 * CATD; idx += 256)
    ((float*)sC)[idx] = cat[(size_t)row0 * CATD + idx];   // rows contiguous
  __syncthreads();

  const int o = tid;
  const float4* __restrict__ w4 = (const float4*)(Wt + (size_t)o * CATD);
  float acc[4] = {0.f, 0.f, 0.f, 0.f};
#pragma unroll 8
  for (int k4 = 0; k4 < CATD / 4; ++k4) {
    const float4 w = w4[k4];
#pragma unroll
    for (int r = 0; r < 4; ++r) {
      const float4 c = ((const float4*)sC[r])[k4];
      acc[r] += c.x * w.x + c.y * w.y + c.z * w.z + c.w * w.w;
    }
  }
  const float bto = bt[o];
  float s1 = 0.f, s2 = 0.f;
#pragma unroll
  for (int r = 0; r < 4; ++r) {
    const float v2 = acc[r] + bto;
    vals[(size_t)(row0 + r) * TRD + o] = v2;
    s1 += v2;
    s2 = fmaf(v2, v2, s2);
  }
  float* sb = stats + (size_t)(bid & (NSTATBUF - 1)) * 2 * TRD;
  atomicAdd(&sb[o], s1);
  atomicAdd(&sb[TRD + o], s2);
}

// ---------------------------------------------------------------------------
// Kernel 4: fused BN-fold + classifier.
// Each block redundantly folds BN stats into effective weights (tiny), then
// computes out[row][c] for 4 rows. 512 blocks x 256 thr.
// ---------------------------------------------------------------------------
__global__ __launch_bounds__(256) void outbn_kernel(
    const float* __restrict__ vals, const float* __restrict__ stats,
    const float* __restrict__ gamma, const float* __restrict__ beta,
    const float* __restrict__ Wc, const float* __restrict__ bc,
    float* __restrict__ out) {
  __shared__ float sW[NCLS][TRD];
  __shared__ float sb[NCLS];
  __shared__ float red[4][NCLS];
  const int tid = threadIdx.x;
  const int o = tid;                   // 0..255
  float s1 = 0.f, s2 = 0.f;
#pragma unroll
  for (int k = 0; k < NSTATBUF; ++k) {
    s1 += stats[k * 2 * TRD + o];
    s2 += stats[k * 2 * TRD + TRD + o];
  }
  const float invN = 1.0f / (float)NROWS;
  const float mu  = s1 * invN;
  const float var = s2 * invN - mu * mu;
  const float inv = 1.0f / sqrtf(var + EPSV);
  const float g = gamma[o] * inv;
  const float bterm = beta[o] - mu * g;
  float v[NCLS];
#pragma unroll
  for (int c = 0; c < NCLS; ++c) {
    const float wc = Wc[c * TRD + o];
    sW[c][o] = wc * g;
    v[c] = wc * bterm;
  }
#pragma unroll
  for (int s = 1; s < 64; s <<= 1) {
#pragma unroll
    for (int c = 0; c < NCLS; ++c) v[c] += __shfl_xor(v[c], s, 64);
  }
  if ((tid & 63) == 0) {
#pragma unroll
    for (int c = 0; c < NCLS; ++c) red[tid >> 6][c] = v[c];
  }
  __syncthreads();
  if (tid < NCLS)
    sb[tid] = bc[tid] + red[0][tid] + red[1][tid] + red[2][tid] + red[3][tid];
  __syncthreads();

  const int lane = tid & 63;
  const int row = blockIdx.x * 4 + (tid >> 6);   // 512 blocks x 4 rows
  float vv[TRD / 64];
#pragma unroll
  for (int t = 0; t < TRD / 64; ++t)
    vv[t] = vals[(size_t)row * TRD + lane + 64 * t];
#pragma unroll
  for (int c = 0; c < NCLS; ++c) {
    float p = 0.f;
#pragma unroll
    for (int t = 0; t < TRD / 64; ++t)
      p = fmaf(vv[t], sW[c][lane + 64 * t], p);
#pragma unroll
    for (int s = 1; s < 64; s <<= 1) p += __shfl_xor(p, s, 64);
    if (lane == 0) out[(size_t)row * NCLS + c] = p + sb[c];
  }
}

// ---------------------------------------------------------------------------
extern "C" void kernel_launch(void* const* d_in, const int* in_sizes, int n_in,
                              void* d_out, int out_size, void* d_ws, size_t ws_size,
                              hipStream_t stream) {
  (void)in_sizes; (void)n_in; (void)out_size; (void)ws_size;
  const float* nodes = (const float*)d_in[0];
  const float* edges = (const float*)d_in[1];
  const float* dist  = (const float*)d_in[2];
  const int*   mask  = (const int*)d_in[3];
  const float* Wq  = (const float*)d_in[4];
  const float* bq  = (const float*)d_in[5];
  const float* Wk  = (const float*)d_in[6];
  const float* bk  = (const float*)d_in[7];
  const float* Wnv = (const float*)d_in[8];
  const float* bnv = (const float*)d_in[9];
  const float* Wev = (const float*)d_in[10];
  const float* bev = (const float*)d_in[11];
  const float* Wt  = (const float*)d_in[12];
  const float* bt  = (const float*)d_in[13];
  const float* gamma = (const float*)d_in[14];
  const float* beta  = (const float*)d_in[15];
  const float* Wc  = (const float*)d_in[16];
  const float* bc  = (const float*)d_in[17];

  float* ws    = (float*)d_ws;
  float* Q     = ws;                               // 2048*128
  float* K     = Q  + (size_t)NROWS * QKD;         // 2048*128
  float* NV    = K  + (size_t)NROWS * QKD;         // 2048*128
  float* cat   = NV + (size_t)NROWS * NVD;         // 2048*160
  float* vals  = cat + (size_t)NROWS * CATD;       // 2048*256
  float* stats = vals + (size_t)NROWS * TRD;       // 8*512 (sum|sqsum)
  float* outp  = (float*)d_out;

  qkv_kernel<<<NROWS / 2, 256, 0, stream>>>(nodes, Wq, bq, Wk, bk, Wnv, bnv,
                                            Q, K, NV, stats);
  attn_kernel<<<NROWS / TI, 256, 0, stream>>>(Q, K, NV, edges, dist, mask,
                                              Wev, bev, cat);
  trans_kernel<<<NROWS / 4, 256, 0, stream>>>(cat, Wt, bt, vals, stats);
  outbn_kernel<<<NROWS / 4, 256, 0, stream>>>(vals, stats, gamma, beta,
                                              Wc, bc, outp);
}